// Round 1
// baseline (718.303 us; speedup 1.0000x reference)
//
#include <hip/hip_runtime.h>
#include <hip/hip_bf16.h>

// ---------------- wave helpers (wave = 64 on gfx950) ----------------
__device__ __forceinline__ float wave_sum(float v){
  #pragma unroll
  for (int m = 32; m; m >>= 1) v += __shfl_xor(v, m, 64);
  return v;
}
__device__ __forceinline__ float wave_max(float v){
  #pragma unroll
  for (int m = 32; m; m >>= 1) v = fmaxf(v, __shfl_xor(v, m, 64));
  return v;
}

// ---------------- fp32 tiled GEMM: C[M,N] = A[M,K] @ B[K,N] ----------------
// 64x64 tile, BK=64, 256 threads, 4x4 microtile. K % 64 == 0, N % 64 == 0.
__global__ __launch_bounds__(256) void gemm64(const float* __restrict__ A,
                                              const float* __restrict__ B,
                                              float* __restrict__ C,
                                              int M, int N, int K){
  __shared__ float As[64][65];   // transposed: As[k][m], +1 pad
  __shared__ float Bs[64][64];
  const int tid  = threadIdx.x;
  const int brow = blockIdx.x * 64;
  const int bcol = blockIdx.y * 64;
  const int tr = (tid >> 4) << 2;   // 0..60, row in tile
  const int tc = (tid & 15) << 2;   // 0..60, col in tile
  float acc[4][4] = {};

  for (int kb = 0; kb < K; kb += 64){
    #pragma unroll
    for (int it = 0; it < 4; ++it){
      int idx = it * 256 + tid;        // 0..1023
      int r   = idx >> 4;              // tile row 0..63
      int c4  = (idx & 15) << 2;       // k-offset 0..60
      float4 v = make_float4(0.f, 0.f, 0.f, 0.f);
      int gr = brow + r;
      if (gr < M) v = *(const float4*)(A + (size_t)gr * K + kb + c4);
      As[c4 + 0][r] = v.x; As[c4 + 1][r] = v.y;
      As[c4 + 2][r] = v.z; As[c4 + 3][r] = v.w;
    }
    #pragma unroll
    for (int it = 0; it < 4; ++it){
      int idx = it * 256 + tid;
      int r   = idx >> 4;              // k row 0..63
      int c4  = (idx & 15) << 2;
      *(float4*)&Bs[r][c4] = *(const float4*)(B + (size_t)(kb + r) * N + bcol + c4);
    }
    __syncthreads();
    #pragma unroll
    for (int k = 0; k < 64; ++k){
      float a0 = As[k][tr], a1 = As[k][tr+1], a2 = As[k][tr+2], a3 = As[k][tr+3];
      float4 b = *(const float4*)&Bs[k][tc];
      acc[0][0] = fmaf(a0, b.x, acc[0][0]); acc[0][1] = fmaf(a0, b.y, acc[0][1]);
      acc[0][2] = fmaf(a0, b.z, acc[0][2]); acc[0][3] = fmaf(a0, b.w, acc[0][3]);
      acc[1][0] = fmaf(a1, b.x, acc[1][0]); acc[1][1] = fmaf(a1, b.y, acc[1][1]);
      acc[1][2] = fmaf(a1, b.z, acc[1][2]); acc[1][3] = fmaf(a1, b.w, acc[1][3]);
      acc[2][0] = fmaf(a2, b.x, acc[2][0]); acc[2][1] = fmaf(a2, b.y, acc[2][1]);
      acc[2][2] = fmaf(a2, b.z, acc[2][2]); acc[2][3] = fmaf(a2, b.w, acc[2][3]);
      acc[3][0] = fmaf(a3, b.x, acc[3][0]); acc[3][1] = fmaf(a3, b.y, acc[3][1]);
      acc[3][2] = fmaf(a3, b.z, acc[3][2]); acc[3][3] = fmaf(a3, b.w, acc[3][3]);
    }
    __syncthreads();
  }
  #pragma unroll
  for (int i = 0; i < 4; ++i){
    int gr = brow + tr + i;
    if (gr < M){
      float4 o = make_float4(acc[i][0], acc[i][1], acc[i][2], acc[i][3]);
      *(float4*)(C + (size_t)gr * N + bcol + tc) = o;
    }
  }
}

// ---------------- per-node attention scores ----------------
// H=4, C=64: block of 256 = 4 waves; wave h reduces channels of head h.
__global__ __launch_bounds__(256) void scores_h4(const float* __restrict__ hx,
                                                 const float* __restrict__ att_s,
                                                 const float* __restrict__ att_d,
                                                 float* __restrict__ a_s,
                                                 float* __restrict__ a_d, int n){
  int node = blockIdx.x;
  int tid = threadIdx.x;
  int h = tid >> 6, lane = tid & 63;
  float v = hx[(size_t)node * 256 + tid];
  float s  = wave_sum(v * att_s[tid]);
  float dd = wave_sum(v * att_d[tid]);
  if (lane == 0){ a_s[node * 4 + h] = s; a_d[node * 4 + h] = dd; }
}

// H=1, C=64: wave per node.
__global__ __launch_bounds__(256) void scores_h1(const float* __restrict__ hx,
                                                 const float* __restrict__ att_s,
                                                 const float* __restrict__ att_d,
                                                 float* __restrict__ a_s,
                                                 float* __restrict__ a_d, int n){
  int wid = blockIdx.x * 4 + (threadIdx.x >> 6);
  int lane = threadIdx.x & 63;
  if (wid >= n) return;
  float v = hx[(size_t)wid * 64 + lane];
  float s  = wave_sum(v * att_s[lane]);
  float dd = wave_sum(v * att_d[lane]);
  if (lane == 0){ a_s[wid] = s; a_d[wid] = dd; }
}

// ---------------- CSR build (group edges by destination) ----------------
__global__ __launch_bounds__(256) void build_deg(const int* __restrict__ ei,
                                                 int E, int N, int* __restrict__ deg){
  int e = blockIdx.x * blockDim.x + threadIdx.x;
  if (e >= E + N) return;
  int dst = (e < E) ? ei[E + e] : (e - E);   // self-loop tail
  atomicAdd(&deg[dst], 1);
}

// single-block exclusive scan of deg[0..n) -> rowptr & pos; rowptr[n]=total
__global__ __launch_bounds__(1024) void scan_kernel(const int* __restrict__ deg,
                                                    int* __restrict__ rowptr,
                                                    int* __restrict__ pos, int n){
  __shared__ int buf[1024];
  __shared__ int carry;
  int tid = threadIdx.x;
  if (tid == 0) carry = 0;
  __syncthreads();
  for (int base = 0; base < n; base += 1024){
    int i = base + tid;
    int v = (i < n) ? deg[i] : 0;
    buf[tid] = v;
    __syncthreads();
    #pragma unroll
    for (int off = 1; off < 1024; off <<= 1){
      int t = (tid >= off) ? buf[tid - off] : 0;
      __syncthreads();
      buf[tid] += t;
      __syncthreads();
    }
    int excl = buf[tid] - v + carry;
    if (i < n){ rowptr[i] = excl; pos[i] = excl; }
    __syncthreads();                 // everyone done reading carry/buf
    if (tid == 0) carry += buf[1023];
    __syncthreads();
  }
  if (threadIdx.x == 0) rowptr[n] = carry;
}

__global__ __launch_bounds__(256) void build_csr(const int* __restrict__ ei,
                                                 int E, int N,
                                                 int* __restrict__ pos,
                                                 int* __restrict__ csr_src){
  int e = blockIdx.x * blockDim.x + threadIdx.x;
  if (e >= E + N) return;
  int src, dst;
  if (e < E){ src = ei[e]; dst = ei[E + e]; }
  else      { src = dst = e - E; }
  int slot = atomicAdd(&pos[dst], 1);
  csr_src[slot] = src;
}

// ---------------- edge softmax (alpha) : one wave per dst ----------------
template<int H>
__global__ __launch_bounds__(256) void alpha_kernel(const int* __restrict__ rowptr,
                                                    const int* __restrict__ csr_src,
                                                    const float* __restrict__ a_s,
                                                    const float* __restrict__ a_d,
                                                    float* __restrict__ alpha, int n){
  int wid = blockIdx.x * 4 + (threadIdx.x >> 6);
  int lane = threadIdx.x & 63;
  if (wid >= n) return;
  int beg = rowptr[wid], end = rowptr[wid + 1];
  float ad[H], mx[H], sm[H];
  #pragma unroll
  for (int h = 0; h < H; ++h){ ad[h] = a_d[(size_t)wid * H + h]; mx[h] = -3.0e38f; sm[h] = 0.f; }

  for (int s = beg + lane; s < end; s += 64){
    int src = csr_src[s];
    #pragma unroll
    for (int h = 0; h < H; ++h){
      float e = a_s[(size_t)src * H + h] + ad[h];
      e = (e >= 0.f) ? e : 0.2f * e;
      mx[h] = fmaxf(mx[h], e);
    }
  }
  #pragma unroll
  for (int h = 0; h < H; ++h) mx[h] = wave_max(mx[h]);

  for (int s = beg + lane; s < end; s += 64){
    int src = csr_src[s];
    #pragma unroll
    for (int h = 0; h < H; ++h){
      float e = a_s[(size_t)src * H + h] + ad[h];
      e = (e >= 0.f) ? e : 0.2f * e;
      sm[h] += __expf(e - mx[h]);
    }
  }
  #pragma unroll
  for (int h = 0; h < H; ++h) sm[h] = wave_sum(sm[h]) + 1e-16f;

  for (int s = beg + lane; s < end; s += 64){
    int src = csr_src[s];
    float o[H];
    #pragma unroll
    for (int h = 0; h < H; ++h){
      float e = a_s[(size_t)src * H + h] + ad[h];
      e = (e >= 0.f) ? e : 0.2f * e;
      o[h] = __expf(e - mx[h]) / sm[h];
    }
    if (H == 4) *(float4*)&alpha[(size_t)s * 4] = make_float4(o[0], o[1], o[2], o[3]);
    else        alpha[s] = o[0];
  }
}

// ---------------- aggregation layer 1: block per dst, thread = channel ----------------
__global__ __launch_bounds__(256) void aggregate1_kernel(const int* __restrict__ rowptr,
                                                         const int* __restrict__ csr_src,
                                                         const float* __restrict__ alpha,
                                                         const float* __restrict__ hx,
                                                         const float* __restrict__ bias,
                                                         float* __restrict__ h1, int n){
  int d = blockIdx.x;
  int tid = threadIdx.x;
  int h = tid >> 6;
  int beg = rowptr[d], end = rowptr[d + 1];
  float acc = 0.f;
  int s = beg;
  if (s < end){
    int src = csr_src[s];
    for (; s < end; ){
      int nxt = (s + 1 < end) ? csr_src[s + 1] : 0;   // prefetch next src
      float al = alpha[(size_t)s * 4 + h];
      acc = fmaf(al, hx[(size_t)src * 256 + tid], acc);
      src = nxt; ++s;
    }
  }
  float o = acc + bias[tid];
  h1[(size_t)d * 256 + tid] = (o > 0.f) ? o : (__expf(o) - 1.f);   // ELU
}

// ---------------- aggregation layer 2: wave per dst ----------------
__global__ __launch_bounds__(256) void aggregate2_kernel(const int* __restrict__ rowptr,
                                                         const int* __restrict__ csr_src,
                                                         const float* __restrict__ alpha,
                                                         const float* __restrict__ hx,
                                                         const float* __restrict__ bias,
                                                         float* __restrict__ out, int n){
  int wid = blockIdx.x * 4 + (threadIdx.x >> 6);
  int lane = threadIdx.x & 63;
  if (wid >= n) return;
  int beg = rowptr[wid], end = rowptr[wid + 1];
  float acc = 0.f;
  int s = beg;
  if (s < end){
    int src = csr_src[s];
    for (; s < end; ){
      int nxt = (s + 1 < end) ? csr_src[s + 1] : 0;
      acc = fmaf(alpha[s], hx[(size_t)src * 64 + lane], acc);
      src = nxt; ++s;
    }
  }
  out[(size_t)wid * 64 + lane] = acc + bias[lane];
}

// ---------------- host launcher ----------------
extern "C" void kernel_launch(void* const* d_in, const int* in_sizes, int n_in,
                              void* d_out, int out_size, void* d_ws, size_t ws_size,
                              hipStream_t stream){
  const float* x        = (const float*)d_in[0];
  const int*   ei       = (const int*)  d_in[1];
  const float* W1       = (const float*)d_in[2];
  const float* att_src1 = (const float*)d_in[3];
  const float* att_dst1 = (const float*)d_in[4];
  const float* b1       = (const float*)d_in[5];
  const float* W2       = (const float*)d_in[6];
  const float* att_src2 = (const float*)d_in[7];
  const float* att_dst2 = (const float*)d_in[8];
  const float* b2       = (const float*)d_in[9];
  float* out = (float*)d_out;

  const int IN = 128, HC = 256, C = 64;
  const int N  = in_sizes[0] / IN;
  const int E  = in_sizes[1] / 2;
  const int ET = E + N;

  // workspace carve-up (256B aligned)
  char* ws = (char*)d_ws;
  size_t off = 0;
  auto carve = [&](size_t bytes) -> char* {
    off = (off + 255) & ~(size_t)255;
    char* p = ws + off;
    off += bytes;
    return p;
  };
  float* hx1    = (float*)carve((size_t)N * HC * 4);
  float* h1     = (float*)carve((size_t)N * HC * 4);
  float* as1    = (float*)carve((size_t)N * 4 * 4);
  float* ad1    = (float*)carve((size_t)N * 4 * 4);
  int*   deg    = (int*)  carve((size_t)N * 4);
  int*   rowptr = (int*)  carve((size_t)(N + 1) * 4);
  int*   pos    = (int*)  carve((size_t)N * 4);
  int*   csr    = (int*)  carve((size_t)ET * 4);
  float* alpha1 = (float*)carve((size_t)ET * 4 * 4);
  // layer-2 temporaries reuse hx1's region (hx1 dead after aggregate1)
  float* hx2    = hx1;                    // N*64
  float* as2    = hx1 + (size_t)N * 64;   // N
  float* ad2    = as2 + N;                // N
  float* alpha2 = ad2 + N;                // ET   (total 4.15M floats << N*256)

  // ---- layer 1 ----
  dim3 g1((N + 63) / 64, HC / 64);
  gemm64<<<g1, 256, 0, stream>>>(x, W1, hx1, N, HC, IN);
  scores_h4<<<N, 256, 0, stream>>>(hx1, att_src1, att_dst1, as1, ad1, N);

  hipMemsetAsync(deg, 0, (size_t)N * 4, stream);
  build_deg<<<(ET + 255) / 256, 256, 0, stream>>>(ei, E, N, deg);
  scan_kernel<<<1, 1024, 0, stream>>>(deg, rowptr, pos, N);
  build_csr<<<(ET + 255) / 256, 256, 0, stream>>>(ei, E, N, pos, csr);

  alpha_kernel<4><<<(N + 3) / 4, 256, 0, stream>>>(rowptr, csr, as1, ad1, alpha1, N);
  aggregate1_kernel<<<N, 256, 0, stream>>>(rowptr, csr, alpha1, hx1, b1, h1, N);

  // ---- layer 2 ----
  dim3 g2((N + 63) / 64, 1);
  gemm64<<<g2, 256, 0, stream>>>(h1, W2, hx2, N, C, HC);
  scores_h1<<<(N + 3) / 4, 256, 0, stream>>>(hx2, att_src2, att_dst2, as2, ad2, N);
  alpha_kernel<1><<<(N + 3) / 4, 256, 0, stream>>>(rowptr, csr, as2, ad2, alpha2, N);
  aggregate2_kernel<<<(N + 3) / 4, 256, 0, stream>>>(rowptr, csr, alpha2, hx2, b2, out, N);
}

// Round 3
// 417.792 us; speedup vs baseline: 1.7193x; 1.7193x over previous
//
#include <hip/hip_runtime.h>
#include <hip/hip_bf16.h>
#include <hip/hip_fp16.h>

// ---------------- wave helpers (wave = 64 on gfx950) ----------------
__device__ __forceinline__ float wave_sum(float v){
  #pragma unroll
  for (int m = 32; m; m >>= 1) v += __shfl_xor(v, m, 64);
  return v;
}
__device__ __forceinline__ float wave_max(float v){
  #pragma unroll
  for (int m = 32; m; m >>= 1) v = fmaxf(v, __shfl_xor(v, m, 64));
  return v;
}
__device__ __forceinline__ float4 wave_max4(float4 v){
  v.x = wave_max(v.x); v.y = wave_max(v.y); v.z = wave_max(v.z); v.w = wave_max(v.w);
  return v;
}
__device__ __forceinline__ float4 wave_sum4(float4 v){
  v.x = wave_sum(v.x); v.y = wave_sum(v.y); v.z = wave_sum(v.z); v.w = wave_sum(v.w);
  return v;
}
__device__ __forceinline__ float leaky(float x){ return (x >= 0.f) ? x : 0.2f * x; }

// ---------------- fp32 tiled GEMM: C[M,N] = A[M,K] @ B[K,N], OutT output ----
__device__ __forceinline__ void store4(float* p, float4 v){ *(float4*)p = v; }
__device__ __forceinline__ void store4(__half* p, float4 v){
  __half2 a = __floats2half2_rn(v.x, v.y);
  __half2 b = __floats2half2_rn(v.z, v.w);
  *(__half2*)p = a; *(__half2*)(p + 2) = b;
}

template<typename OutT>
__global__ __launch_bounds__(256) void gemm64(const float* __restrict__ A,
                                              const float* __restrict__ B,
                                              OutT* __restrict__ C,
                                              int M, int N, int K){
  __shared__ float As[64][65];   // transposed: As[k][m], +1 pad
  __shared__ float Bs[64][64];
  const int tid  = threadIdx.x;
  const int brow = blockIdx.x * 64;
  const int bcol = blockIdx.y * 64;
  const int tr = (tid >> 4) << 2;
  const int tc = (tid & 15) << 2;
  float acc[4][4] = {};

  for (int kb = 0; kb < K; kb += 64){
    #pragma unroll
    for (int it = 0; it < 4; ++it){
      int idx = it * 256 + tid;
      int r   = idx >> 4;
      int c4  = (idx & 15) << 2;
      float4 v = make_float4(0.f, 0.f, 0.f, 0.f);
      int gr = brow + r;
      if (gr < M) v = *(const float4*)(A + (size_t)gr * K + kb + c4);
      As[c4 + 0][r] = v.x; As[c4 + 1][r] = v.y;
      As[c4 + 2][r] = v.z; As[c4 + 3][r] = v.w;
    }
    #pragma unroll
    for (int it = 0; it < 4; ++it){
      int idx = it * 256 + tid;
      int r   = idx >> 4;
      int c4  = (idx & 15) << 2;
      *(float4*)&Bs[r][c4] = *(const float4*)(B + (size_t)(kb + r) * N + bcol + c4);
    }
    __syncthreads();
    #pragma unroll
    for (int k = 0; k < 64; ++k){
      float a0 = As[k][tr], a1 = As[k][tr+1], a2 = As[k][tr+2], a3 = As[k][tr+3];
      float4 b = *(const float4*)&Bs[k][tc];
      acc[0][0] = fmaf(a0, b.x, acc[0][0]); acc[0][1] = fmaf(a0, b.y, acc[0][1]);
      acc[0][2] = fmaf(a0, b.z, acc[0][2]); acc[0][3] = fmaf(a0, b.w, acc[0][3]);
      acc[1][0] = fmaf(a1, b.x, acc[1][0]); acc[1][1] = fmaf(a1, b.y, acc[1][1]);
      acc[1][2] = fmaf(a1, b.z, acc[1][2]); acc[1][3] = fmaf(a1, b.w, acc[1][3]);
      acc[2][0] = fmaf(a2, b.x, acc[2][0]); acc[2][1] = fmaf(a2, b.y, acc[2][1]);
      acc[2][2] = fmaf(a2, b.z, acc[2][2]); acc[2][3] = fmaf(a2, b.w, acc[2][3]);
      acc[3][0] = fmaf(a3, b.x, acc[3][0]); acc[3][1] = fmaf(a3, b.y, acc[3][1]);
      acc[3][2] = fmaf(a3, b.z, acc[3][2]); acc[3][3] = fmaf(a3, b.w, acc[3][3]);
    }
    __syncthreads();
  }
  #pragma unroll
  for (int i = 0; i < 4; ++i){
    int gr = brow + tr + i;
    if (gr < M)
      store4(C + (size_t)gr * N + bcol + tc,
             make_float4(acc[i][0], acc[i][1], acc[i][2], acc[i][3]));
  }
}

// ---------------- per-node attention scores (fp16 hx input) ----------------
__global__ __launch_bounds__(256) void scores_h4(const __half* __restrict__ hx,
                                                 const float* __restrict__ att_s,
                                                 const float* __restrict__ att_d,
                                                 float* __restrict__ a_s,
                                                 float* __restrict__ a_d, int n){
  int node = blockIdx.x;
  int tid = threadIdx.x;
  int h = tid >> 6, lane = tid & 63;
  float v = __half2float(hx[(size_t)node * 256 + tid]);
  float s  = wave_sum(v * att_s[tid]);
  float dd = wave_sum(v * att_d[tid]);
  if (lane == 0){ a_s[node * 4 + h] = s; a_d[node * 4 + h] = dd; }
}

__global__ __launch_bounds__(256) void scores_h1(const __half* __restrict__ hx,
                                                 const float* __restrict__ att_s,
                                                 const float* __restrict__ att_d,
                                                 float* __restrict__ a_s,
                                                 float* __restrict__ a_d, int n){
  int wid = blockIdx.x * 4 + (threadIdx.x >> 6);
  int lane = threadIdx.x & 63;
  if (wid >= n) return;
  float v = __half2float(hx[(size_t)wid * 64 + lane]);
  float s  = wave_sum(v * att_s[lane]);
  float dd = wave_sum(v * att_d[lane]);
  if (lane == 0){ a_s[wid] = s; a_d[wid] = dd; }
}

// ---------------- CSR build (group edges by destination) ----------------
__global__ __launch_bounds__(256) void build_deg(const int* __restrict__ ei,
                                                 int E, int N, int* __restrict__ deg){
  int e = blockIdx.x * blockDim.x + threadIdx.x;
  if (e >= E + N) return;
  int dst = (e < E) ? ei[E + e] : (e - E);
  atomicAdd(&deg[dst], 1);
}

// 3-phase exclusive scan of deg[0..n) -> rowptr (+pos), rowptr[n]=total
__global__ __launch_bounds__(1024) void scan_phase1(const int* __restrict__ deg,
                                                    int* __restrict__ rowptr,
                                                    int* __restrict__ bsum, int n){
  __shared__ int buf[1024];
  int tid = threadIdx.x;
  int i = blockIdx.x * 1024 + tid;
  int v = (i < n) ? deg[i] : 0;
  buf[tid] = v;
  __syncthreads();
  #pragma unroll
  for (int off = 1; off < 1024; off <<= 1){
    int t = (tid >= off) ? buf[tid - off] : 0;
    __syncthreads();
    buf[tid] += t;
    __syncthreads();
  }
  if (i < n) rowptr[i] = buf[tid] - v;         // exclusive within block
  if (tid == 1023) bsum[blockIdx.x] = buf[1023];
}

__global__ __launch_bounds__(64) void scan_phase2(const int* __restrict__ bsum,
                                                  int* __restrict__ boff,
                                                  int* __restrict__ rowptr,
                                                  int nb, int n){
  int lane = threadIdx.x;
  int v = (lane < nb) ? bsum[lane] : 0;
  int orig = v;
  #pragma unroll
  for (int off = 1; off < 64; off <<= 1){
    int t = __shfl_up(v, off, 64);
    if (lane >= off) v += t;
  }
  if (lane < nb) boff[lane] = v - orig;
  if (lane == nb - 1) rowptr[n] = v;
}

__global__ __launch_bounds__(1024) void scan_phase3(int* __restrict__ rowptr,
                                                    int* __restrict__ pos,
                                                    const int* __restrict__ boff, int n){
  int i = blockIdx.x * 1024 + threadIdx.x;
  if (i >= n) return;
  int val = rowptr[i] + boff[blockIdx.x];
  rowptr[i] = val;
  pos[i] = val;
}

__global__ __launch_bounds__(256) void build_csr(const int* __restrict__ ei,
                                                 int E, int N,
                                                 int* __restrict__ pos,
                                                 int* __restrict__ csr_src){
  int e = blockIdx.x * blockDim.x + threadIdx.x;
  if (e >= E + N) return;
  int src, dst;
  if (e < E){ src = ei[e]; dst = ei[E + e]; }
  else      { src = dst = e - E; }
  int slot = atomicAdd(&pos[dst], 1);
  csr_src[slot] = src;
}

// ---- fused softmax + aggregation, layer 1 (H=4, C=64; fp16 payload) ----
// wave per dst; lane owns channels [4l, 4l+4); head h = l>>4.
__global__ __launch_bounds__(256) void fused_agg1(const int* __restrict__ rowptr,
                                                  const int* __restrict__ csr,
                                                  const float* __restrict__ a_s,
                                                  const float* __restrict__ a_d,
                                                  const __half* __restrict__ hx,
                                                  const float* __restrict__ bias,
                                                  float* __restrict__ h1, int n){
  int d = blockIdx.x * 4 + (threadIdx.x >> 6);
  int l = threadIdx.x & 63;
  if (d >= n) return;
  int h = l >> 4;
  int beg = rowptr[d], end = rowptr[d + 1];
  float4 ad4 = *(const float4*)(a_d + (size_t)d * 4);

  // pass A: per-head max of raw scores (leaky is monotonic -> apply after)
  float4 mx = make_float4(-3e38f, -3e38f, -3e38f, -3e38f);
  for (int s = beg + l; s < end; s += 64){
    int src = csr[s];
    float4 as4 = *(const float4*)(a_s + (size_t)src * 4);
    mx.x = fmaxf(mx.x, as4.x + ad4.x); mx.y = fmaxf(mx.y, as4.y + ad4.y);
    mx.z = fmaxf(mx.z, as4.z + ad4.z); mx.w = fmaxf(mx.w, as4.w + ad4.w);
  }
  mx = wave_max4(mx);
  mx.x = leaky(mx.x); mx.y = leaky(mx.y); mx.z = leaky(mx.z); mx.w = leaky(mx.w);

  // pass B: chunked; lane pre-gathers its edge's index + unnormalized p4
  float4 acc = make_float4(0.f, 0.f, 0.f, 0.f);
  float4 sum = make_float4(0.f, 0.f, 0.f, 0.f);
  for (int base = beg; base < end; base += 64){
    int m = min(64, end - base);
    int i = base + l;
    bool in = (i < end);
    int idx = in ? csr[i] : 0;
    float4 as4 = *(const float4*)(a_s + (size_t)idx * 4);
    float4 p4;
    p4.x = in ? __expf(leaky(as4.x + ad4.x) - mx.x) : 0.f;
    p4.y = in ? __expf(leaky(as4.y + ad4.y) - mx.y) : 0.f;
    p4.z = in ? __expf(leaky(as4.z + ad4.z) - mx.z) : 0.f;
    p4.w = in ? __expf(leaky(as4.w + ad4.w) - mx.w) : 0.f;
    sum.x += p4.x; sum.y += p4.y; sum.z += p4.z; sum.w += p4.w;

    auto step = [&](int j){
      int src = __shfl(idx, j, 64);
      float pa = __shfl(p4.x, j, 64);
      float pb = __shfl(p4.y, j, 64);
      float pc = __shfl(p4.z, j, 64);
      float pd = __shfl(p4.w, j, 64);
      float pj = (h == 0) ? pa : (h == 1) ? pb : (h == 2) ? pc : pd;
      const __half2* hp = (const __half2*)(hx + (size_t)src * 256 + (l << 2));
      float2 f0 = __half22float2(hp[0]);
      float2 f1 = __half22float2(hp[1]);
      acc.x = fmaf(pj, f0.x, acc.x); acc.y = fmaf(pj, f0.y, acc.y);
      acc.z = fmaf(pj, f1.x, acc.z); acc.w = fmaf(pj, f1.y, acc.w);
    };
    int j = 0;
    for (; j + 4 <= m; j += 4){ step(j); step(j + 1); step(j + 2); step(j + 3); }
    for (; j < m; ++j) step(j);
  }
  sum = wave_sum4(sum);
  float sh = (h == 0) ? sum.x : (h == 1) ? sum.y : (h == 2) ? sum.z : sum.w;
  float inv = 1.f / (sh + 1e-16f);
  float4 b4 = *(const float4*)(bias + (l << 2));
  float4 o;
  o.x = acc.x * inv + b4.x; o.y = acc.y * inv + b4.y;
  o.z = acc.z * inv + b4.z; o.w = acc.w * inv + b4.w;
  o.x = (o.x > 0.f) ? o.x : (__expf(o.x) - 1.f);
  o.y = (o.y > 0.f) ? o.y : (__expf(o.y) - 1.f);
  o.z = (o.z > 0.f) ? o.z : (__expf(o.z) - 1.f);
  o.w = (o.w > 0.f) ? o.w : (__expf(o.w) - 1.f);
  *(float4*)(h1 + (size_t)d * 256 + (l << 2)) = o;
}

// ---- fused softmax + aggregation, layer 2 (H=1, C=64; fp16 payload) ----
// wave per dst; lane l: pair = l>>5 handles alternating edges, c2 = l&31 owns
// channels {2c2, 2c2+1}; cross-pair combine at the end via shfl_xor(32).
__global__ __launch_bounds__(256) void fused_agg2(const int* __restrict__ rowptr,
                                                  const int* __restrict__ csr,
                                                  const float* __restrict__ a_s,
                                                  const float* __restrict__ a_d,
                                                  const __half* __restrict__ hx,
                                                  const float* __restrict__ bias,
                                                  float* __restrict__ out, int n){
  int d = blockIdx.x * 4 + (threadIdx.x >> 6);
  int l = threadIdx.x & 63;
  if (d >= n) return;
  int pair = l >> 5, c2 = l & 31;
  int beg = rowptr[d], end = rowptr[d + 1];
  float ad = a_d[d];

  float mx = -3e38f;
  for (int s = beg + l; s < end; s += 64)
    mx = fmaxf(mx, a_s[csr[s]] + ad);
  mx = leaky(wave_max(mx));

  float2 acc = make_float2(0.f, 0.f);
  float sum = 0.f;
  for (int base = beg; base < end; base += 64){
    int m = min(64, end - base);
    int i = base + l;
    bool in = (i < end);
    int idx = in ? csr[i] : 0;
    float pl = in ? __expf(leaky(a_s[idx] + ad) - mx) : 0.f;
    sum += pl;

    auto step = [&](int j){
      int jj = j + pair;                 // jj >= m lanes carry p=0 -> no-op
      int src = __shfl(idx, jj, 64);
      float pj = __shfl(pl, jj, 64);
      __half2 u = *(const __half2*)(hx + (size_t)src * 64 + (c2 << 1));
      float2 f = __half22float2(u);
      acc.x = fmaf(pj, f.x, acc.x);
      acc.y = fmaf(pj, f.y, acc.y);
    };
    int j = 0;
    for (; j + 4 <= m; j += 4){ step(j); step(j + 2); }
    for (; j < m; j += 2) step(j);
  }
  sum = wave_sum(sum);
  acc.x += __shfl_xor(acc.x, 32, 64);
  acc.y += __shfl_xor(acc.y, 32, 64);
  if (pair == 0){
    float inv = 1.f / (sum + 1e-16f);
    float2 o;
    o.x = acc.x * inv + bias[c2 * 2];
    o.y = acc.y * inv + bias[c2 * 2 + 1];
    *(float2*)(out + (size_t)d * 64 + (c2 << 1)) = o;
  }
}

// ---------------- host launcher ----------------
extern "C" void kernel_launch(void* const* d_in, const int* in_sizes, int n_in,
                              void* d_out, int out_size, void* d_ws, size_t ws_size,
                              hipStream_t stream){
  const float* x        = (const float*)d_in[0];
  const int*   ei       = (const int*)  d_in[1];
  const float* W1       = (const float*)d_in[2];
  const float* att_src1 = (const float*)d_in[3];
  const float* att_dst1 = (const float*)d_in[4];
  const float* b1       = (const float*)d_in[5];
  const float* W2       = (const float*)d_in[6];
  const float* att_src2 = (const float*)d_in[7];
  const float* att_dst2 = (const float*)d_in[8];
  const float* b2       = (const float*)d_in[9];
  float* out = (float*)d_out;

  const int IN = 128, HC = 256, C = 64;
  const int N  = in_sizes[0] / IN;
  const int E  = in_sizes[1] / 2;
  const int ET = E + N;
  const int NB = (N + 1023) / 1024;      // <= 64 assumed (N <= 65536)

  char* ws = (char*)d_ws;
  size_t off = 0;
  auto carve = [&](size_t bytes) -> char* {
    off = (off + 255) & ~(size_t)255;
    char* p = ws + off;
    off += bytes;
    return p;
  };
  __half* hx1h  = (__half*)carve((size_t)N * HC * 2);
  float*  h1    = (float*) carve((size_t)N * HC * 4);
  float*  as1   = (float*) carve((size_t)N * 4 * 4);
  float*  ad1   = (float*) carve((size_t)N * 4 * 4);
  __half* hx2h  = (__half*)carve((size_t)N * C * 2);
  float*  as2   = (float*) carve((size_t)N * 4);
  float*  ad2   = (float*) carve((size_t)N * 4);
  int*    deg   = (int*)   carve((size_t)N * 4);
  int*    rowptr= (int*)   carve((size_t)(N + 1) * 4);
  int*    pos   = (int*)   carve((size_t)N * 4);
  int*    csr   = (int*)   carve((size_t)ET * 4);
  int*    bsum  = (int*)   carve(64 * 4);
  int*    boff  = (int*)   carve(64 * 4);

  // ---- CSR build ----
  hipMemsetAsync(deg, 0, (size_t)N * 4, stream);
  build_deg<<<(ET + 255) / 256, 256, 0, stream>>>(ei, E, N, deg);
  scan_phase1<<<NB, 1024, 0, stream>>>(deg, rowptr, bsum, N);
  scan_phase2<<<1, 64, 0, stream>>>(bsum, boff, rowptr, NB, N);
  scan_phase3<<<NB, 1024, 0, stream>>>(rowptr, pos, boff, N);
  build_csr<<<(ET + 255) / 256, 256, 0, stream>>>(ei, E, N, pos, csr);

  // ---- layer 1 ----
  dim3 g1((N + 63) / 64, HC / 64);
  gemm64<__half><<<g1, 256, 0, stream>>>(x, W1, hx1h, N, HC, IN);
  scores_h4<<<N, 256, 0, stream>>>(hx1h, att_src1, att_dst1, as1, ad1, N);
  fused_agg1<<<(N + 3) / 4, 256, 0, stream>>>(rowptr, csr, as1, ad1, hx1h, b1, h1, N);

  // ---- layer 2 ----
  dim3 g2((N + 63) / 64, C / 64);
  gemm64<__half><<<g2, 256, 0, stream>>>(h1, W2, hx2h, N, C, HC);
  scores_h1<<<(N + 3) / 4, 256, 0, stream>>>(hx2h, att_src2, att_dst2, as2, ad2, N);
  fused_agg2<<<(N + 3) / 4, 256, 0, stream>>>(rowptr, csr, as2, ad2, hx2h, b2, out, N);
}

// Round 4
// 402.188 us; speedup vs baseline: 1.7860x; 1.0388x over previous
//
#include <hip/hip_runtime.h>
#include <hip/hip_bf16.h>
#include <hip/hip_fp16.h>

__device__ __forceinline__ float leaky(float x){ return (x >= 0.f) ? x : 0.2f * x; }

// ---- fp32 tiled GEMM + fused attention-score epilogue, fp16 output ----
// C[M,N] = A[M,K] @ B[K,N]; each 64-col block tile == one head (N = H*64).
// Epilogue: a_s[row,h] = sum_c C[row, h*64+c]*att_s[h,c] (fp32 acc, exact).
__global__ __launch_bounds__(256) void gemm64(const float* __restrict__ A,
                                              const float* __restrict__ B,
                                              __half* __restrict__ C,
                                              const float* __restrict__ att_s_w,
                                              const float* __restrict__ att_d_w,
                                              float* __restrict__ a_s_out,
                                              float* __restrict__ a_d_out,
                                              int M, int N, int K, int H){
  __shared__ float As[64][65];   // transposed: As[k][m], +1 pad
  __shared__ float Bs[64][64];
  const int tid  = threadIdx.x;
  const int brow = blockIdx.x * 64;
  const int bcol = blockIdx.y * 64;
  const int hh   = blockIdx.y;          // head index (64 cols per head)
  const int tr = (tid >> 4) << 2;
  const int tc = (tid & 15) << 2;
  float acc[4][4] = {};

  for (int kb = 0; kb < K; kb += 64){
    #pragma unroll
    for (int it = 0; it < 4; ++it){
      int idx = it * 256 + tid;
      int r   = idx >> 4;
      int c4  = (idx & 15) << 2;
      float4 v = make_float4(0.f, 0.f, 0.f, 0.f);
      int gr = brow + r;
      if (gr < M) v = *(const float4*)(A + (size_t)gr * K + kb + c4);
      As[c4 + 0][r] = v.x; As[c4 + 1][r] = v.y;
      As[c4 + 2][r] = v.z; As[c4 + 3][r] = v.w;
    }
    #pragma unroll
    for (int it = 0; it < 4; ++it){
      int idx = it * 256 + tid;
      int r   = idx >> 4;
      int c4  = (idx & 15) << 2;
      *(float4*)&Bs[r][c4] = *(const float4*)(B + (size_t)(kb + r) * N + bcol + c4);
    }
    __syncthreads();
    #pragma unroll
    for (int k = 0; k < 64; ++k){
      float a0 = As[k][tr], a1 = As[k][tr+1], a2 = As[k][tr+2], a3 = As[k][tr+3];
      float4 b = *(const float4*)&Bs[k][tc];
      acc[0][0] = fmaf(a0, b.x, acc[0][0]); acc[0][1] = fmaf(a0, b.y, acc[0][1]);
      acc[0][2] = fmaf(a0, b.z, acc[0][2]); acc[0][3] = fmaf(a0, b.w, acc[0][3]);
      acc[1][0] = fmaf(a1, b.x, acc[1][0]); acc[1][1] = fmaf(a1, b.y, acc[1][1]);
      acc[1][2] = fmaf(a1, b.z, acc[1][2]); acc[1][3] = fmaf(a1, b.w, acc[1][3]);
      acc[2][0] = fmaf(a2, b.x, acc[2][0]); acc[2][1] = fmaf(a2, b.y, acc[2][1]);
      acc[2][2] = fmaf(a2, b.z, acc[2][2]); acc[2][3] = fmaf(a2, b.w, acc[2][3]);
      acc[3][0] = fmaf(a3, b.x, acc[3][0]); acc[3][1] = fmaf(a3, b.y, acc[3][1]);
      acc[3][2] = fmaf(a3, b.z, acc[3][2]); acc[3][3] = fmaf(a3, b.w, acc[3][3]);
    }
    __syncthreads();
  }

  // fp16 store of hx
  #pragma unroll
  for (int i = 0; i < 4; ++i){
    int gr = brow + tr + i;
    if (gr < M){
      __half2 u0 = __floats2half2_rn(acc[i][0], acc[i][1]);
      __half2 u1 = __floats2half2_rn(acc[i][2], acc[i][3]);
      __half* p = C + (size_t)gr * N + bcol + tc;
      *(__half2*)p = u0; *(__half2*)(p + 2) = u1;
    }
  }

  // fused scores: reduce acc[i][:] * att over the 16 lanes sharing the rows
  float ws[4], wd[4];
  #pragma unroll
  for (int jj = 0; jj < 4; ++jj){
    ws[jj] = att_s_w[hh * 64 + tc + jj];
    wd[jj] = att_d_w[hh * 64 + tc + jj];
  }
  #pragma unroll
  for (int i = 0; i < 4; ++i){
    float s = 0.f, dd = 0.f;
    #pragma unroll
    for (int jj = 0; jj < 4; ++jj){
      s  = fmaf(acc[i][jj], ws[jj], s);
      dd = fmaf(acc[i][jj], wd[jj], dd);
    }
    #pragma unroll
    for (int m = 1; m < 16; m <<= 1){
      s  += __shfl_xor(s,  m, 64);
      dd += __shfl_xor(dd, m, 64);
    }
    int gr = brow + tr + i;
    if ((tid & 15) == 0 && gr < M){
      a_s_out[(size_t)gr * H + hh] = s;
      a_d_out[(size_t)gr * H + hh] = dd;
    }
  }
}

// ---------------- CSR build (group edges by destination) ----------------
__global__ __launch_bounds__(256) void build_deg(const int* __restrict__ ei,
                                                 int E, int N, int* __restrict__ deg){
  int e = blockIdx.x * blockDim.x + threadIdx.x;
  if (e >= E + N) return;
  int dst = (e < E) ? ei[E + e] : (e - E);
  atomicAdd(&deg[dst], 1);
}

// 3-phase exclusive scan of deg[0..n) -> rowptr (+pos), rowptr[n]=total
__global__ __launch_bounds__(1024) void scan_phase1(const int* __restrict__ deg,
                                                    int* __restrict__ rowptr,
                                                    int* __restrict__ bsum, int n){
  __shared__ int buf[1024];
  int tid = threadIdx.x;
  int i = blockIdx.x * 1024 + tid;
  int v = (i < n) ? deg[i] : 0;
  buf[tid] = v;
  __syncthreads();
  #pragma unroll
  for (int off = 1; off < 1024; off <<= 1){
    int t = (tid >= off) ? buf[tid - off] : 0;
    __syncthreads();
    buf[tid] += t;
    __syncthreads();
  }
  if (i < n) rowptr[i] = buf[tid] - v;
  if (tid == 1023) bsum[blockIdx.x] = buf[1023];
}

__global__ __launch_bounds__(64) void scan_phase2(const int* __restrict__ bsum,
                                                  int* __restrict__ boff,
                                                  int* __restrict__ rowptr,
                                                  int nb, int n){
  int lane = threadIdx.x;
  int v = (lane < nb) ? bsum[lane] : 0;
  int orig = v;
  #pragma unroll
  for (int off = 1; off < 64; off <<= 1){
    int t = __shfl_up(v, off, 64);
    if (lane >= off) v += t;
  }
  if (lane < nb) boff[lane] = v - orig;
  if (lane == nb - 1) rowptr[n] = v;
}

__global__ __launch_bounds__(1024) void scan_phase3(int* __restrict__ rowptr,
                                                    int* __restrict__ pos,
                                                    const int* __restrict__ boff, int n){
  int i = blockIdx.x * 1024 + threadIdx.x;
  if (i >= n) return;
  int val = rowptr[i] + boff[blockIdx.x];
  rowptr[i] = val;
  pos[i] = val;
}

__global__ __launch_bounds__(256) void build_csr(const int* __restrict__ ei,
                                                 int E, int N,
                                                 int* __restrict__ pos,
                                                 int* __restrict__ csr_src){
  int e = blockIdx.x * blockDim.x + threadIdx.x;
  if (e >= E + N) return;
  int src, dst;
  if (e < E){ src = ei[e]; dst = ei[E + e]; }
  else      { src = dst = e - E; }
  int slot = atomicAdd(&pos[dst], 1);
  csr_src[slot] = src;
}

// ---- fused softmax + aggregation, layer 1 (H=4, flat C=256; fp16 payload) ----
// wave per dst; lane owns flat channels [4l,4l+4), head h = l>>4.
// No max-shift (|e|<=~10 -> exp safe in fp32); every lane redundantly computes
// its head's p, so there are NO cross-lane ops. csr[j] is wave-uniform ->
// scalar load. Depth-2 software pipeline on {a_s, payload} gathers.
__global__ __launch_bounds__(256) void fused_agg1(const int* __restrict__ rowptr,
                                                  const int* __restrict__ csr,
                                                  const float* __restrict__ a_s,
                                                  const float* __restrict__ a_d,
                                                  const __half* __restrict__ hx,
                                                  const float* __restrict__ bias,
                                                  float* __restrict__ h1, int n){
  int d = blockIdx.x * 4 + (threadIdx.x >> 6);
  if (d >= n) return;
  int l = threadIdx.x & 63;
  int h_ = l >> 4;
  int beg = __builtin_amdgcn_readfirstlane(rowptr[d]);
  int end = __builtin_amdgcn_readfirstlane(rowptr[d + 1]);
  float adh = a_d[d * 4 + h_];

  float4 acc = make_float4(0.f, 0.f, 0.f, 0.f);
  float sum = 0.f;

  // slots (deg >= 1 always: self-loop)
  float e0, e1; uint2 r0, r1;
  {
    int s0 = csr[beg];
    e0 = a_s[s0 * 4 + h_];
    r0 = *((const uint2*)(hx + (size_t)s0 * 256) + l);
  }
  const bool two = (beg + 1 < end);
  if (two){
    int s1 = csr[beg + 1];
    e1 = a_s[s1 * 4 + h_];
    r1 = *((const uint2*)(hx + (size_t)s1 * 256) + l);
  }
  for (int j = beg + 2; j < end; ++j){
    int s2 = csr[j];
    float e2 = a_s[s2 * 4 + h_];
    uint2 r2 = *((const uint2*)(hx + (size_t)s2 * 256) + l);
    float p = __expf(leaky(e0 + adh));
    sum += p;
    float2 f0 = __half22float2(*(__half2*)&r0.x);
    float2 f1 = __half22float2(*(__half2*)&r0.y);
    acc.x = fmaf(p, f0.x, acc.x); acc.y = fmaf(p, f0.y, acc.y);
    acc.z = fmaf(p, f1.x, acc.z); acc.w = fmaf(p, f1.y, acc.w);
    e0 = e1; r0 = r1;
    e1 = e2; r1 = r2;
  }
  {
    float p = __expf(leaky(e0 + adh));
    sum += p;
    float2 f0 = __half22float2(*(__half2*)&r0.x);
    float2 f1 = __half22float2(*(__half2*)&r0.y);
    acc.x = fmaf(p, f0.x, acc.x); acc.y = fmaf(p, f0.y, acc.y);
    acc.z = fmaf(p, f1.x, acc.z); acc.w = fmaf(p, f1.y, acc.w);
  }
  if (two){
    float p = __expf(leaky(e1 + adh));
    sum += p;
    float2 f0 = __half22float2(*(__half2*)&r1.x);
    float2 f1 = __half22float2(*(__half2*)&r1.y);
    acc.x = fmaf(p, f0.x, acc.x); acc.y = fmaf(p, f0.y, acc.y);
    acc.z = fmaf(p, f1.x, acc.z); acc.w = fmaf(p, f1.y, acc.w);
  }

  float inv = 1.f / (sum + 1e-16f);
  float4 b4 = *(const float4*)(bias + (l << 2));
  float4 o;
  o.x = acc.x * inv + b4.x; o.y = acc.y * inv + b4.y;
  o.z = acc.z * inv + b4.z; o.w = acc.w * inv + b4.w;
  o.x = (o.x > 0.f) ? o.x : (__expf(o.x) - 1.f);
  o.y = (o.y > 0.f) ? o.y : (__expf(o.y) - 1.f);
  o.z = (o.z > 0.f) ? o.z : (__expf(o.z) - 1.f);
  o.w = (o.w > 0.f) ? o.w : (__expf(o.w) - 1.f);
  *(float4*)(h1 + (size_t)d * 256 + (l << 2)) = o;
}

// ---- fused softmax + aggregation, layer 2 (H=1, C=64; fp16 payload) ----
// wave per dst; lane owns channel l. p is wave-uniform, computed redundantly.
__global__ __launch_bounds__(256) void fused_agg2(const int* __restrict__ rowptr,
                                                  const int* __restrict__ csr,
                                                  const float* __restrict__ a_s,
                                                  const float* __restrict__ a_d,
                                                  const __half* __restrict__ hx,
                                                  const float* __restrict__ bias,
                                                  float* __restrict__ out, int n){
  int d = blockIdx.x * 4 + (threadIdx.x >> 6);
  if (d >= n) return;
  int l = threadIdx.x & 63;
  int beg = __builtin_amdgcn_readfirstlane(rowptr[d]);
  int end = __builtin_amdgcn_readfirstlane(rowptr[d + 1]);
  float ad = a_d[d];

  float acc = 0.f, sum = 0.f;
  float e0, e1; __half r0, r1;
  {
    int s0 = csr[beg];
    e0 = a_s[s0];
    r0 = hx[(size_t)s0 * 64 + l];
  }
  const bool two = (beg + 1 < end);
  if (two){
    int s1 = csr[beg + 1];
    e1 = a_s[s1];
    r1 = hx[(size_t)s1 * 64 + l];
  }
  for (int j = beg + 2; j < end; ++j){
    int s2 = csr[j];
    float e2 = a_s[s2];
    __half r2 = hx[(size_t)s2 * 64 + l];
    float p = __expf(leaky(e0 + ad));
    sum += p;
    acc = fmaf(p, __half2float(r0), acc);
    e0 = e1; r0 = r1;
    e1 = e2; r1 = r2;
  }
  {
    float p = __expf(leaky(e0 + ad));
    sum += p;
    acc = fmaf(p, __half2float(r0), acc);
  }
  if (two){
    float p = __expf(leaky(e1 + ad));
    sum += p;
    acc = fmaf(p, __half2float(r1), acc);
  }
  out[(size_t)d * 64 + l] = acc / (sum + 1e-16f) + bias[l];
}

// ---------------- host launcher ----------------
extern "C" void kernel_launch(void* const* d_in, const int* in_sizes, int n_in,
                              void* d_out, int out_size, void* d_ws, size_t ws_size,
                              hipStream_t stream){
  const float* x        = (const float*)d_in[0];
  const int*   ei       = (const int*)  d_in[1];
  const float* W1       = (const float*)d_in[2];
  const float* att_src1 = (const float*)d_in[3];
  const float* att_dst1 = (const float*)d_in[4];
  const float* b1       = (const float*)d_in[5];
  const float* W2       = (const float*)d_in[6];
  const float* att_src2 = (const float*)d_in[7];
  const float* att_dst2 = (const float*)d_in[8];
  const float* b2       = (const float*)d_in[9];
  float* out = (float*)d_out;

  const int IN = 128, HC = 256, C = 64;
  const int N  = in_sizes[0] / IN;
  const int E  = in_sizes[1] / 2;
  const int ET = E + N;
  const int NB = (N + 1023) / 1024;      // <= 64 assumed (N <= 65536)

  char* ws = (char*)d_ws;
  size_t off = 0;
  auto carve = [&](size_t bytes) -> char* {
    off = (off + 255) & ~(size_t)255;
    char* p = ws + off;
    off += bytes;
    return p;
  };
  __half* hx1h  = (__half*)carve((size_t)N * HC * 2);
  float*  h1    = (float*) carve((size_t)N * HC * 4);
  float*  as1   = (float*) carve((size_t)N * 4 * 4);
  float*  ad1   = (float*) carve((size_t)N * 4 * 4);
  __half* hx2h  = (__half*)carve((size_t)N * C * 2);
  float*  as2   = (float*) carve((size_t)N * 4);
  float*  ad2   = (float*) carve((size_t)N * 4);
  int*    deg   = (int*)   carve((size_t)N * 4);
  int*    rowptr= (int*)   carve((size_t)(N + 1) * 4);
  int*    pos   = (int*)   carve((size_t)N * 4);
  int*    csr   = (int*)   carve((size_t)ET * 4);
  int*    bsum  = (int*)   carve(64 * 4);
  int*    boff  = (int*)   carve(64 * 4);

  // ---- CSR build ----
  hipMemsetAsync(deg, 0, (size_t)N * 4, stream);
  build_deg<<<(ET + 255) / 256, 256, 0, stream>>>(ei, E, N, deg);
  scan_phase1<<<NB, 1024, 0, stream>>>(deg, rowptr, bsum, N);
  scan_phase2<<<1, 64, 0, stream>>>(bsum, boff, rowptr, NB, N);
  scan_phase3<<<NB, 1024, 0, stream>>>(rowptr, pos, boff, N);
  build_csr<<<(ET + 255) / 256, 256, 0, stream>>>(ei, E, N, pos, csr);

  // ---- layer 1: GEMM (+scores epilogue) then fused softmax-aggregate ----
  dim3 g1((N + 63) / 64, HC / 64);
  gemm64<<<g1, 256, 0, stream>>>(x, W1, hx1h, att_src1, att_dst1, as1, ad1,
                                 N, HC, IN, 4);
  fused_agg1<<<(N + 3) / 4, 256, 0, stream>>>(rowptr, csr, as1, ad1, hx1h, b1, h1, N);

  // ---- layer 2 ----
  dim3 g2((N + 63) / 64, C / 64);
  gemm64<<<g2, 256, 0, stream>>>(h1, W2, hx2h, att_src2, att_dst2, as2, ad2,
                                 N, C, HC, 1);
  fused_agg2<<<(N + 3) / 4, 256, 0, stream>>>(rowptr, csr, as2, ad2, hx2h, b2, out, N);
}

// Round 6
// 338.954 us; speedup vs baseline: 2.1192x; 1.1866x over previous
//
#include <hip/hip_runtime.h>
#include <hip/hip_bf16.h>
#include <hip/hip_fp16.h>

using f16x8 = __attribute__((ext_vector_type(8))) _Float16;
using f32x4 = __attribute__((ext_vector_type(4))) float;

__device__ __forceinline__ float leaky(float x){ return (x >= 0.f) ? x : 0.2f * x; }

// ---------------- x fp32 -> fp16 (vectorized) ----------------
__global__ __launch_bounds__(256) void f32_to_f16(const float* __restrict__ in,
                                                  __half* __restrict__ out, size_t n4){
  size_t i = (size_t)blockIdx.x * 256 + threadIdx.x;
  size_t stride = (size_t)gridDim.x * 256;
  for (; i < n4; i += stride){
    float4 v = ((const float4*)in)[i];
    __half2 a = __floats2half2_rn(v.x, v.y);
    __half2 b = __floats2half2_rn(v.z, v.w);
    uint2 u = make_uint2(*(unsigned*)&a, *(unsigned*)&b);
    *(uint2*)(out + i * 4) = u;
  }
}

// ---- pack W [K][N] fp32 into fp16 B-fragment order for mfma 16x16x32 ----
// Wf[((ksg*(N/16) + ntg)*64 + lane)*8 + j] = W[ksg*32 + (lane>>4)*8 + j][ntg*16 + (lane&15)]
__global__ __launch_bounds__(256) void pack_W(const float* __restrict__ W,
                                              __half* __restrict__ Wf, int K, int N){
  int t = blockIdx.x * 256 + threadIdx.x;
  if (t >= K * N) return;
  int j    = t & 7;
  int lane = (t >> 3) & 63;
  int rest = t >> 9;
  int nt16 = N >> 4;
  int ntg  = rest % nt16;
  int ksg  = rest / nt16;
  int k = ksg * 32 + ((lane >> 4) << 3) + j;
  int n = ntg * 16 + (lane & 15);
  Wf[t] = __float2half_rn(W[(size_t)k * N + n]);
}

// ---- MFMA fp16 GEMM + fused score epilogue ----
// C[M,N](fp16) = A[M,K](fp16) @ W; W pre-packed in fragment order.
// Block: 256 thr = 4 waves; tile 64(M)x64(N); wave w owns rows [w*16, w*16+16).
// A staged in LDS with XOR swizzle (c8 ^ ((r&7)<<3)) -> conflict-free frag reads.
// Epilogue: a_s[row,head] = sum_c C[row, head*64+c] * att_s[head,c]; head = bcol/64.
__global__ __launch_bounds__(256) void gemm_mfma(const __half* __restrict__ A,
                                                 const __half* __restrict__ Wf,
                                                 __half* __restrict__ C,
                                                 const float* __restrict__ att_s_w,
                                                 const float* __restrict__ att_d_w,
                                                 float* __restrict__ a_s_out,
                                                 float* __restrict__ a_d_out,
                                                 int M, int N, int K, int H){
  __shared__ __half As[64 * 64];
  const int tid  = threadIdx.x;
  const int l    = tid & 63;
  const int w    = tid >> 6;
  const int brow = blockIdx.x * 64;
  const int bcol = blockIdx.y * 64;
  const int NT16 = N >> 4;
  const int cl   = l & 15;        // col (C/D) / row-in-tile (A)
  const int kg   = l >> 4;        // k-group
  const int arow = w * 16 + cl;   // A row within block tile

  f32x4 acc[4] = {};

  for (int kb = 0; kb < K; kb += 64){
    #pragma unroll
    for (int s = tid; s < 512; s += 256){
      int r  = s >> 3;
      int c8 = (s & 7) << 3;
      uint4 v = make_uint4(0u, 0u, 0u, 0u);
      if (brow + r < M) v = *(const uint4*)(A + (size_t)(brow + r) * K + kb + c8);
      *(uint4*)&As[r * 64 + (c8 ^ ((r & 7) << 3))] = v;
    }
    __syncthreads();
    #pragma unroll
    for (int ks = 0; ks < 2; ++ks){
      int ckk = ks * 32 + kg * 8;
      f16x8 af = *(const f16x8*)&As[arow * 64 + (ckk ^ ((arow & 7) << 3))];
      int ksg = (kb >> 5) + ks;
      const __half* wbase = Wf + ((size_t)(ksg * NT16 + (bcol >> 4)) * 64 + l) * 8;
      #pragma unroll
      for (int nt = 0; nt < 4; ++nt){
        f16x8 bf = *(const f16x8*)(wbase + (size_t)nt * 512);
        acc[nt] = __builtin_amdgcn_mfma_f32_16x16x32_f16(af, bf, acc[nt], 0, 0, 0);
      }
    }
    __syncthreads();
  }

  // epilogue: fp16 store of C + fused attention scores
  const int head = bcol >> 6;
  float aws[4], awd[4];
  #pragma unroll
  for (int nt = 0; nt < 4; ++nt){
    aws[nt] = att_s_w[bcol + nt * 16 + cl];
    awd[nt] = att_d_w[bcol + nt * 16 + cl];
  }
  #pragma unroll
  for (int i = 0; i < 4; ++i){
    int row = brow + w * 16 + kg * 4 + i;
    bool ok = row < M;
    float s = 0.f, dd = 0.f;
    #pragma unroll
    for (int nt = 0; nt < 4; ++nt){
      float c = acc[nt][i];
      if (ok) C[(size_t)row * N + bcol + nt * 16 + cl] = __float2half_rn(c);
      s  = fmaf(c, aws[nt], s);
      dd = fmaf(c, awd[nt], dd);
    }
    #pragma unroll
    for (int m = 1; m < 16; m <<= 1){
      s  += __shfl_xor(s,  m, 64);
      dd += __shfl_xor(dd, m, 64);
    }
    if (ok && cl == 0){
      a_s_out[(size_t)row * H + head] = s;
      a_d_out[(size_t)row * H + head] = dd;
    }
  }
}

// ---------------- CSR build (group edges by destination) ----------------
__global__ __launch_bounds__(256) void build_deg(const int* __restrict__ ei,
                                                 int E, int N, int* __restrict__ deg){
  int e = blockIdx.x * blockDim.x + threadIdx.x;
  if (e >= E + N) return;
  int dst = (e < E) ? ei[E + e] : (e - E);
  atomicAdd(&deg[dst], 1);
}

__global__ __launch_bounds__(1024) void scan_phase1(const int* __restrict__ deg,
                                                    int* __restrict__ rowptr,
                                                    int* __restrict__ bsum, int n){
  __shared__ int buf[1024];
  int tid = threadIdx.x;
  int i = blockIdx.x * 1024 + tid;
  int v = (i < n) ? deg[i] : 0;
  buf[tid] = v;
  __syncthreads();
  #pragma unroll
  for (int off = 1; off < 1024; off <<= 1){
    int t = (tid >= off) ? buf[tid - off] : 0;
    __syncthreads();
    buf[tid] += t;
    __syncthreads();
  }
  if (i < n) rowptr[i] = buf[tid] - v;
  if (tid == 1023) bsum[blockIdx.x] = buf[1023];
}

__global__ __launch_bounds__(64) void scan_phase2(const int* __restrict__ bsum,
                                                  int* __restrict__ boff,
                                                  int* __restrict__ rowptr,
                                                  int nb, int n){
  int lane = threadIdx.x;
  int v = (lane < nb) ? bsum[lane] : 0;
  int orig = v;
  #pragma unroll
  for (int off = 1; off < 64; off <<= 1){
    int t = __shfl_up(v, off, 64);
    if (lane >= off) v += t;
  }
  if (lane < nb) boff[lane] = v - orig;
  if (lane == nb - 1) rowptr[n] = v;
}

__global__ __launch_bounds__(1024) void scan_phase3(int* __restrict__ rowptr,
                                                    int* __restrict__ pos,
                                                    const int* __restrict__ boff, int n){
  int i = blockIdx.x * 1024 + threadIdx.x;
  if (i >= n) return;
  int val = rowptr[i] + boff[blockIdx.x];
  rowptr[i] = val;
  pos[i] = val;
}

__global__ __launch_bounds__(256) void build_csr(const int* __restrict__ ei,
                                                 int E, int N,
                                                 int* __restrict__ pos,
                                                 int* __restrict__ csr_src){
  int e = blockIdx.x * blockDim.x + threadIdx.x;
  if (e >= E + N) return;
  int src, dst;
  if (e < E){ src = ei[e]; dst = ei[E + e]; }
  else      { src = dst = e - E; }
  int slot = atomicAdd(&pos[dst], 1);
  csr_src[slot] = src;
}

// ---- fused softmax + aggregation, layer 1 (H=4, flat C=256; fp16 payload) ----
// wave per dst; lane owns flat channels [4l,4l+4), head = l>>4. No max-shift
// (|e| small -> exp safe in fp32); p computed redundantly per lane (no
// cross-lane ops); csr[j] wave-uniform -> scalar load; depth-2 pipeline.
// Output h1 in fp16 (feeds layer-2 MFMA GEMM).
__global__ __launch_bounds__(256) void fused_agg1(const int* __restrict__ rowptr,
                                                  const int* __restrict__ csr,
                                                  const float* __restrict__ a_s,
                                                  const float* __restrict__ a_d,
                                                  const __half* __restrict__ hx,
                                                  const float* __restrict__ bias,
                                                  __half* __restrict__ h1, int n){
  int d = blockIdx.x * 4 + (threadIdx.x >> 6);
  if (d >= n) return;
  int l = threadIdx.x & 63;
  int h_ = l >> 4;
  int beg = __builtin_amdgcn_readfirstlane(rowptr[d]);
  int end = __builtin_amdgcn_readfirstlane(rowptr[d + 1]);
  float adh = a_d[d * 4 + h_];

  float4 acc = make_float4(0.f, 0.f, 0.f, 0.f);
  float sum = 0.f;

  float e0, e1; uint2 r0, r1;
  {
    int s0 = csr[beg];
    e0 = a_s[s0 * 4 + h_];
    r0 = *((const uint2*)(hx + (size_t)s0 * 256) + l);
  }
  const bool two = (beg + 1 < end);
  if (two){
    int s1 = csr[beg + 1];
    e1 = a_s[s1 * 4 + h_];
    r1 = *((const uint2*)(hx + (size_t)s1 * 256) + l);
  }
  for (int j = beg + 2; j < end; ++j){
    int s2 = csr[j];
    float e2 = a_s[s2 * 4 + h_];
    uint2 r2 = *((const uint2*)(hx + (size_t)s2 * 256) + l);
    float p = __expf(leaky(e0 + adh));
    sum += p;
    float2 f0 = __half22float2(*(__half2*)&r0.x);
    float2 f1 = __half22float2(*(__half2*)&r0.y);
    acc.x = fmaf(p, f0.x, acc.x); acc.y = fmaf(p, f0.y, acc.y);
    acc.z = fmaf(p, f1.x, acc.z); acc.w = fmaf(p, f1.y, acc.w);
    e0 = e1; r0 = r1;
    e1 = e2; r1 = r2;
  }
  {
    float p = __expf(leaky(e0 + adh));
    sum += p;
    float2 f0 = __half22float2(*(__half2*)&r0.x);
    float2 f1 = __half22float2(*(__half2*)&r0.y);
    acc.x = fmaf(p, f0.x, acc.x); acc.y = fmaf(p, f0.y, acc.y);
    acc.z = fmaf(p, f1.x, acc.z); acc.w = fmaf(p, f1.y, acc.w);
  }
  if (two){
    float p = __expf(leaky(e1 + adh));
    sum += p;
    float2 f0 = __half22float2(*(__half2*)&r1.x);
    float2 f1 = __half22float2(*(__half2*)&r1.y);
    acc.x = fmaf(p, f0.x, acc.x); acc.y = fmaf(p, f0.y, acc.y);
    acc.z = fmaf(p, f1.x, acc.z); acc.w = fmaf(p, f1.y, acc.w);
  }

  float inv = 1.f / (sum + 1e-16f);
  float4 b4 = *(const float4*)(bias + (l << 2));
  float4 o;
  o.x = acc.x * inv + b4.x; o.y = acc.y * inv + b4.y;
  o.z = acc.z * inv + b4.z; o.w = acc.w * inv + b4.w;
  o.x = (o.x > 0.f) ? o.x : (__expf(o.x) - 1.f);
  o.y = (o.y > 0.f) ? o.y : (__expf(o.y) - 1.f);
  o.z = (o.z > 0.f) ? o.z : (__expf(o.z) - 1.f);
  o.w = (o.w > 0.f) ? o.w : (__expf(o.w) - 1.f);
  __half2 u0 = __floats2half2_rn(o.x, o.y);
  __half2 u1 = __floats2half2_rn(o.z, o.w);
  uint2 uu = make_uint2(*(unsigned*)&u0, *(unsigned*)&u1);
  *(uint2*)(h1 + (size_t)d * 256 + (l << 2)) = uu;
}

// ---- fused softmax + aggregation, layer 2 (H=1, C=64; fp16 payload) ----
__global__ __launch_bounds__(256) void fused_agg2(const int* __restrict__ rowptr,
                                                  const int* __restrict__ csr,
                                                  const float* __restrict__ a_s,
                                                  const float* __restrict__ a_d,
                                                  const __half* __restrict__ hx,
                                                  const float* __restrict__ bias,
                                                  float* __restrict__ out, int n){
  int d = blockIdx.x * 4 + (threadIdx.x >> 6);
  if (d >= n) return;
  int l = threadIdx.x & 63;
  int beg = __builtin_amdgcn_readfirstlane(rowptr[d]);
  int end = __builtin_amdgcn_readfirstlane(rowptr[d + 1]);
  float ad = a_d[d];

  float acc = 0.f, sum = 0.f;
  float e0, e1; __half r0, r1;
  {
    int s0 = csr[beg];
    e0 = a_s[s0];
    r0 = hx[(size_t)s0 * 64 + l];
  }
  const bool two = (beg + 1 < end);
  if (two){
    int s1 = csr[beg + 1];
    e1 = a_s[s1];
    r1 = hx[(size_t)s1 * 64 + l];
  }
  for (int j = beg + 2; j < end; ++j){
    int s2 = csr[j];
    float e2 = a_s[s2];
    __half r2 = hx[(size_t)s2 * 64 + l];
    float p = __expf(leaky(e0 + ad));
    sum += p;
    acc = fmaf(p, __half2float(r0), acc);
    e0 = e1; r0 = r1;
    e1 = e2; r1 = r2;
  }
  {
    float p = __expf(leaky(e0 + ad));
    sum += p;
    acc = fmaf(p, __half2float(r0), acc);
  }
  if (two){
    float p = __expf(leaky(e1 + ad));
    sum += p;
    acc = fmaf(p, __half2float(r1), acc);
  }
  out[(size_t)d * 64 + l] = acc / (sum + 1e-16f) + bias[l];
}

// ---------------- host launcher ----------------
extern "C" void kernel_launch(void* const* d_in, const int* in_sizes, int n_in,
                              void* d_out, int out_size, void* d_ws, size_t ws_size,
                              hipStream_t stream){
  const float* x        = (const float*)d_in[0];
  const int*   ei       = (const int*)  d_in[1];
  const float* W1       = (const float*)d_in[2];
  const float* att_src1 = (const float*)d_in[3];
  const float* att_dst1 = (const float*)d_in[4];
  const float* b1       = (const float*)d_in[5];
  const float* W2       = (const float*)d_in[6];
  const float* att_src2 = (const float*)d_in[7];
  const float* att_dst2 = (const float*)d_in[8];
  const float* b2       = (const float*)d_in[9];
  float* out = (float*)d_out;

  const int IN = 128, HC = 256, C = 64;
  const int N  = in_sizes[0] / IN;
  const int E  = in_sizes[1] / 2;
  const int ET = E + N;
  const int NB = (N + 1023) / 1024;      // <= 64 assumed (N <= 65536)

  char* ws = (char*)d_ws;
  size_t off = 0;
  auto carve = [&](size_t bytes) -> char* {
    off = (off + 255) & ~(size_t)255;
    char* p = ws + off;
    off += bytes;
    return p;
  };
  __half* xh    = (__half*)carve((size_t)N * IN * 2);
  __half* W1f   = (__half*)carve((size_t)IN * HC * 2);
  __half* W2f   = (__half*)carve((size_t)HC * C * 2);
  __half* hx1h  = (__half*)carve((size_t)N * HC * 2);
  __half* h1h   = (__half*)carve((size_t)N * HC * 2);
  __half* hx2h  = (__half*)carve((size_t)N * C * 2);
  float*  as1   = (float*) carve((size_t)N * 4 * 4);
  float*  ad1   = (float*) carve((size_t)N * 4 * 4);
  float*  as2   = (float*) carve((size_t)N * 4);
  float*  ad2   = (float*) carve((size_t)N * 4);
  int*    deg   = (int*)   carve((size_t)N * 4);
  int*    rowptr= (int*)   carve((size_t)(N + 1) * 4);
  int*    pos   = (int*)   carve((size_t)N * 4);
  int*    csr   = (int*)   carve((size_t)ET * 4);
  int*    bsum  = (int*)   carve(64 * 4);
  int*    boff  = (int*)   carve(64 * 4);

  // ---- prep: x -> fp16, W -> fragment-packed fp16 ----
  f32_to_f16<<<2048, 256, 0, stream>>>(x, xh, (size_t)N * IN / 4);
  pack_W<<<(IN * HC + 255) / 256, 256, 0, stream>>>(W1, W1f, IN, HC);
  pack_W<<<(HC * C + 255) / 256, 256, 0, stream>>>(W2, W2f, HC, C);

  // ---- CSR build ----
  hipMemsetAsync(deg, 0, (size_t)N * 4, stream);
  build_deg<<<(ET + 255) / 256, 256, 0, stream>>>(ei, E, N, deg);
  scan_phase1<<<NB, 1024, 0, stream>>>(deg, rowptr, bsum, N);
  scan_phase2<<<1, 64, 0, stream>>>(bsum, boff, rowptr, NB, N);
  scan_phase3<<<NB, 1024, 0, stream>>>(rowptr, pos, boff, N);
  build_csr<<<(ET + 255) / 256, 256, 0, stream>>>(ei, E, N, pos, csr);

  // ---- layer 1: MFMA GEMM (+scores epilogue), fused softmax-aggregate ----
  dim3 g1((N + 63) / 64, HC / 64);
  gemm_mfma<<<g1, 256, 0, stream>>>(xh, W1f, hx1h, att_src1, att_dst1,
                                    as1, ad1, N, HC, IN, 4);
  fused_agg1<<<(N + 3) / 4, 256, 0, stream>>>(rowptr, csr, as1, ad1, hx1h, b1, h1h, N);

  // ---- layer 2 ----
  dim3 g2((N + 63) / 64, C / 64);
  gemm_mfma<<<g2, 256, 0, stream>>>(h1h, W2f, hx2h, att_src2, att_dst2,
                                    as2, ad2, N, C, HC, 1);
  fused_agg2<<<(N + 3) / 4, 256, 0, stream>>>(rowptr, csr, as2, ad2, hx2h, b2, out, N);
}

// Round 13
// 318.642 us; speedup vs baseline: 2.2543x; 1.0637x over previous
//
#include <hip/hip_runtime.h>
#include <hip/hip_bf16.h>
#include <hip/hip_fp16.h>

using f16x8 = __attribute__((ext_vector_type(8))) _Float16;
using f32x4 = __attribute__((ext_vector_type(4))) float;

__device__ __forceinline__ float leaky(float x){ return (x >= 0.f) ? x : 0.2f * x; }

// ---- device helper: pack one element of W [K][N] into B-fragment order ----
// Wf[((ksg*(N/16)+ntg)*64+lane)*8+j] = W[ksg*32+(lane>>4)*8+j][ntg*16+(lane&15)]
__device__ __forceinline__ void pack_w_elem(const float* __restrict__ W,
                                            __half* __restrict__ Wf,
                                            int t, int N){
  int j    = t & 7;
  int lane = (t >> 3) & 63;
  int rest = t >> 9;
  int nt16 = N >> 4;
  int ntg  = rest % nt16;
  int ksg  = rest / nt16;
  int k = ksg * 32 + ((lane >> 4) << 3) + j;
  int n = ntg * 16 + (lane & 15);
  Wf[t] = __float2half_rn(W[(size_t)k * N + n]);
}

// ---- prep: x fp32->fp16, pack W1/W2, zero deg (single dispatch) ----
__global__ __launch_bounds__(256) void prep_kernel(const float* __restrict__ x,
                                                   __half* __restrict__ xh, size_t n4,
                                                   const float* __restrict__ W1,
                                                   __half* __restrict__ W1f, int kn1, int n1,
                                                   const float* __restrict__ W2,
                                                   __half* __restrict__ W2f, int kn2, int n2,
                                                   int* __restrict__ deg, int N){
  size_t gid = (size_t)blockIdx.x * 256 + threadIdx.x;
  size_t stride = (size_t)gridDim.x * 256;
  for (size_t i = gid; i < n4; i += stride){
    float4 v = ((const float4*)x)[i];
    __half2 a = __floats2half2_rn(v.x, v.y);
    __half2 b = __floats2half2_rn(v.z, v.w);
    uint2 u = make_uint2(*(unsigned*)&a, *(unsigned*)&b);
    *(uint2*)(xh + i * 4) = u;
  }
  for (size_t t = gid; t < (size_t)kn1; t += stride) pack_w_elem(W1, W1f, (int)t, n1);
  for (size_t t = gid; t < (size_t)kn2; t += stride) pack_w_elem(W2, W2f, (int)t, n2);
  for (size_t i = gid; i < (size_t)N; i += stride) deg[i] = 0;
}

// ---- MFMA fp16 GEMM + fused score epilogue ----
__global__ __launch_bounds__(256) void gemm_mfma(const __half* __restrict__ A,
                                                 const __half* __restrict__ Wf,
                                                 __half* __restrict__ C,
                                                 const float* __restrict__ att_s_w,
                                                 const float* __restrict__ att_d_w,
                                                 float* __restrict__ a_s_out,
                                                 float* __restrict__ a_d_out,
                                                 int M, int N, int K, int H){
  __shared__ __half As[64 * 64];
  const int tid  = threadIdx.x;
  const int l    = tid & 63;
  const int w    = tid >> 6;
  const int brow = blockIdx.x * 64;
  const int bcol = blockIdx.y * 64;
  const int NT16 = N >> 4;
  const int cl   = l & 15;
  const int kg   = l >> 4;
  const int arow = w * 16 + cl;

  f32x4 acc[4] = {};

  for (int kb = 0; kb < K; kb += 64){
    #pragma unroll
    for (int s = tid; s < 512; s += 256){
      int r  = s >> 3;
      int c8 = (s & 7) << 3;
      uint4 v = make_uint4(0u, 0u, 0u, 0u);
      if (brow + r < M) v = *(const uint4*)(A + (size_t)(brow + r) * K + kb + c8);
      *(uint4*)&As[r * 64 + (c8 ^ ((r & 7) << 3))] = v;
    }
    __syncthreads();
    #pragma unroll
    for (int ks = 0; ks < 2; ++ks){
      int ckk = ks * 32 + kg * 8;
      f16x8 af = *(const f16x8*)&As[arow * 64 + (ckk ^ ((arow & 7) << 3))];
      int ksg = (kb >> 5) + ks;
      const __half* wbase = Wf + ((size_t)(ksg * NT16 + (bcol >> 4)) * 64 + l) * 8;
      #pragma unroll
      for (int nt = 0; nt < 4; ++nt){
        f16x8 bf = *(const f16x8*)(wbase + (size_t)nt * 512);
        acc[nt] = __builtin_amdgcn_mfma_f32_16x16x32_f16(af, bf, acc[nt], 0, 0, 0);
      }
    }
    __syncthreads();
  }

  const int head = bcol >> 6;
  float aws[4], awd[4];
  #pragma unroll
  for (int nt = 0; nt < 4; ++nt){
    aws[nt] = att_s_w[bcol + nt * 16 + cl];
    awd[nt] = att_d_w[bcol + nt * 16 + cl];
  }
  #pragma unroll
  for (int i = 0; i < 4; ++i){
    int row = brow + w * 16 + kg * 4 + i;
    bool ok = row < M;
    float s = 0.f, dd = 0.f;
    #pragma unroll
    for (int nt = 0; nt < 4; ++nt){
      float c = acc[nt][i];
      if (ok) C[(size_t)row * N + bcol + nt * 16 + cl] = __float2half_rn(c);
      s  = fmaf(c, aws[nt], s);
      dd = fmaf(c, awd[nt], dd);
    }
    #pragma unroll
    for (int m = 1; m < 16; m <<= 1){
      s  += __shfl_xor(s,  m, 64);
      dd += __shfl_xor(dd, m, 64);
    }
    if (ok && cl == 0){
      a_s_out[(size_t)row * H + head] = s;
      a_d_out[(size_t)row * H + head] = dd;
    }
  }
}

// ---------------- CSR build ----------------
__global__ __launch_bounds__(256) void build_deg(const int* __restrict__ ei,
                                                 int E, int N, int* __restrict__ deg){
  int e = blockIdx.x * blockDim.x + threadIdx.x;
  if (e >= E + N) return;
  int dst = (e < E) ? ei[E + e] : (e - E);
  atomicAdd(&deg[dst], 1);
}

__global__ __launch_bounds__(1024) void scan_phase1(const int* __restrict__ deg,
                                                    int* __restrict__ rowptr,
                                                    int* __restrict__ bsum, int n){
  __shared__ int buf[1024];
  int tid = threadIdx.x;
  int i = blockIdx.x * 1024 + tid;
  int v = (i < n) ? deg[i] : 0;
  buf[tid] = v;
  __syncthreads();
  #pragma unroll
  for (int off = 1; off < 1024; off <<= 1){
    int t = (tid >= off) ? buf[tid - off] : 0;
    __syncthreads();
    buf[tid] += t;
    __syncthreads();
  }
  if (i < n) rowptr[i] = buf[tid] - v;
  if (tid == 1023) bsum[blockIdx.x] = buf[1023];
}

// phase3 with phase2 folded in: wave 0 of every block recomputes the <=64-wide
// prefix of bsum, block adds its own offset. Block 0 also writes rowptr[n].
__global__ __launch_bounds__(1024) void scan_phase3(int* __restrict__ rowptr,
                                                    int* __restrict__ pos,
                                                    const int* __restrict__ bsum,
                                                    int nb, int n){
  __shared__ int s_off;
  __shared__ int s_tot;
  int tid = threadIdx.x;
  if (tid < 64){
    int v = (tid < nb) ? bsum[tid] : 0;
    int orig = v;
    #pragma unroll
    for (int off = 1; off < 64; off <<= 1){
      int t = __shfl_up(v, off, 64);
      if (tid >= off) v += t;
    }
    if (tid == (int)blockIdx.x) s_off = v - orig;
    if (tid == nb - 1) s_tot = v;
  }
  __syncthreads();
  if (blockIdx.x == 0 && tid == 0) rowptr[n] = s_tot;
  int i = blockIdx.x * 1024 + tid;
  if (i >= n) return;
  int val = rowptr[i] + s_off;
  rowptr[i] = val;
  pos[i] = val;
}

__global__ __launch_bounds__(256) void build_csr(const int* __restrict__ ei,
                                                 int E, int N,
                                                 int* __restrict__ pos,
                                                 int* __restrict__ csr_src){
  int e = blockIdx.x * blockDim.x + threadIdx.x;
  if (e >= E + N) return;
  int src, dst;
  if (e < E){ src = ei[e]; dst = ei[E + e]; }
  else      { src = dst = e - E; }
  int slot = atomicAdd(&pos[dst], 1);
  csr_src[slot] = src;
}

// ---- fused softmax + aggregation, layer 1 (H=4, flat C=256; fp16 payload) ----
// wave per dst; lane owns flat channels [4l,4l+4), head = l>>4.
// Batch-4 double-buffered pipeline (named buffers -> static reg indexing):
// up to 4 payload gathers in flight while consuming the previous 4.
__global__ __launch_bounds__(256) void fused_agg1(const int* __restrict__ rowptr,
                                                  const int* __restrict__ csr,
                                                  const float* __restrict__ a_s,
                                                  const float* __restrict__ a_d,
                                                  const __half* __restrict__ hx,
                                                  const float* __restrict__ bias,
                                                  __half* __restrict__ h1, int n){
  int d = blockIdx.x * 4 + (threadIdx.x >> 6);
  if (d >= n) return;
  int l = threadIdx.x & 63;
  int h_ = l >> 4;
  int beg = __builtin_amdgcn_readfirstlane(rowptr[d]);
  int end = __builtin_amdgcn_readfirstlane(rowptr[d + 1]);
  float adh = a_d[d * 4 + h_];

  float4 acc = make_float4(0.f, 0.f, 0.f, 0.f);
  float sum = 0.f;

  auto LOAD = [&](int j0, float (&e)[4], uint2 (&r)[4]){
    #pragma unroll
    for (int t = 0; t < 4; ++t){
      int j = j0 + t;
      int s = (j < end) ? csr[j] : csr[beg];
      e[t] = a_s[s * 4 + h_];
      r[t] = *((const uint2*)(hx + (size_t)s * 256) + l);
    }
  };
  auto CONS = [&](int j0, float (&e)[4], uint2 (&r)[4]){
    #pragma unroll
    for (int t = 0; t < 4; ++t){
      bool in = (j0 + t < end);
      float p = in ? __expf(leaky(e[t] + adh)) : 0.f;
      sum += p;
      float2 f0 = __half22float2(*(__half2*)&r[t].x);
      float2 f1 = __half22float2(*(__half2*)&r[t].y);
      acc.x = fmaf(p, f0.x, acc.x); acc.y = fmaf(p, f0.y, acc.y);
      acc.z = fmaf(p, f1.x, acc.z); acc.w = fmaf(p, f1.y, acc.w);
    }
  };

  float eA[4], eB[4]; uint2 rA[4], rB[4];
  int j0 = beg;
  LOAD(j0, eA, rA);
  while (true){
    int j1 = j0 + 4;
    if (j1 < end) LOAD(j1, eB, rB);
    CONS(j0, eA, rA);
    j0 = j1; if (j0 >= end) break;
    j1 = j0 + 4;
    if (j1 < end) LOAD(j1, eA, rA);
    CONS(j0, eB, rB);
    j0 = j1; if (j0 >= end) break;
  }

  float inv = 1.f / (sum + 1e-16f);
  float4 b4 = *(const float4*)(bias + (l << 2));
  float4 o;
  o.x = acc.x * inv + b4.x; o.y = acc.y * inv + b4.y;
  o.z = acc.z * inv + b4.z; o.w = acc.w * inv + b4.w;
  o.x = (o.x > 0.f) ? o.x : (__expf(o.x) - 1.f);
  o.y = (o.y > 0.f) ? o.y : (__expf(o.y) - 1.f);
  o.z = (o.z > 0.f) ? o.z : (__expf(o.z) - 1.f);
  o.w = (o.w > 0.f) ? o.w : (__expf(o.w) - 1.f);
  __half2 u0 = __floats2half2_rn(o.x, o.y);
  __half2 u1 = __floats2half2_rn(o.z, o.w);
  uint2 uu = make_uint2(*(unsigned*)&u0, *(unsigned*)&u1);
  *(uint2*)(h1 + (size_t)d * 256 + (l << 2)) = uu;
}

// ---- fused softmax + aggregation, layer 2 (H=1, C=64; fp16 payload) ----
// Same batch-4 double-buffered structure; lane owns channel l.
__global__ __launch_bounds__(256) void fused_agg2(const int* __restrict__ rowptr,
                                                  const int* __restrict__ csr,
                                                  const float* __restrict__ a_s,
                                                  const float* __restrict__ a_d,
                                                  const __half* __restrict__ hx,
                                                  const float* __restrict__ bias,
                                                  float* __restrict__ out, int n){
  int d = blockIdx.x * 4 + (threadIdx.x >> 6);
  if (d >= n) return;
  int l = threadIdx.x & 63;
  int beg = __builtin_amdgcn_readfirstlane(rowptr[d]);
  int end = __builtin_amdgcn_readfirstlane(rowptr[d + 1]);
  float ad = a_d[d];

  float acc = 0.f, sum = 0.f;

  auto LOAD = [&](int j0, float (&e)[4], unsigned short (&r)[4]){
    #pragma unroll
    for (int t = 0; t < 4; ++t){
      int j = j0 + t;
      int s = (j < end) ? csr[j] : csr[beg];
      e[t] = a_s[s];
      r[t] = *(const unsigned short*)(hx + (size_t)s * 64 + l);
    }
  };
  auto CONS = [&](int j0, float (&e)[4], unsigned short (&r)[4]){
    #pragma unroll
    for (int t = 0; t < 4; ++t){
      bool in = (j0 + t < end);
      float p = in ? __expf(leaky(e[t] + ad)) : 0.f;
      sum += p;
      acc = fmaf(p, __half2float(*(__half*)&r[t]), acc);
    }
  };

  float eA[4], eB[4]; unsigned short rA[4], rB[4];
  int j0 = beg;
  LOAD(j0, eA, rA);
  while (true){
    int j1 = j0 + 4;
    if (j1 < end) LOAD(j1, eB, rB);
    CONS(j0, eA, rA);
    j0 = j1; if (j0 >= end) break;
    j1 = j0 + 4;
    if (j1 < end) LOAD(j1, eA, rA);
    CONS(j0, eB, rB);
    j0 = j1; if (j0 >= end) break;
  }

  out[(size_t)d * 64 + l] = acc / (sum + 1e-16f) + bias[l];
}

// ---------------- host launcher ----------------
extern "C" void kernel_launch(void* const* d_in, const int* in_sizes, int n_in,
                              void* d_out, int out_size, void* d_ws, size_t ws_size,
                              hipStream_t stream){
  const float* x        = (const float*)d_in[0];
  const int*   ei       = (const int*)  d_in[1];
  const float* W1       = (const float*)d_in[2];
  const float* att_src1 = (const float*)d_in[3];
  const float* att_dst1 = (const float*)d_in[4];
  const float* b1       = (const float*)d_in[5];
  const float* W2       = (const float*)d_in[6];
  const float* att_src2 = (const float*)d_in[7];
  const float* att_dst2 = (const float*)d_in[8];
  const float* b2       = (const float*)d_in[9];
  float* out = (float*)d_out;

  const int IN = 128, HC = 256, C = 64;
  const int N  = in_sizes[0] / IN;
  const int E  = in_sizes[1] / 2;
  const int ET = E + N;
  const int NB = (N + 1023) / 1024;      // <= 64 assumed (N <= 65536)

  char* ws = (char*)d_ws;
  size_t off = 0;
  auto carve = [&](size_t bytes) -> char* {
    off = (off + 255) & ~(size_t)255;
    char* p = ws + off;
    off += bytes;
    return p;
  };
  __half* xh    = (__half*)carve((size_t)N * IN * 2);
  __half* W1f   = (__half*)carve((size_t)IN * HC * 2);
  __half* W2f   = (__half*)carve((size_t)HC * C * 2);
  __half* hx1h  = (__half*)carve((size_t)N * HC * 2);
  __half* h1h   = (__half*)carve((size_t)N * HC * 2);
  __half* hx2h  = (__half*)carve((size_t)N * C * 2);
  float*  as1   = (float*) carve((size_t)N * 4 * 4);
  float*  ad1   = (float*) carve((size_t)N * 4 * 4);
  float*  as2   = (float*) carve((size_t)N * 4);
  float*  ad2   = (float*) carve((size_t)N * 4);
  int*    deg   = (int*)   carve((size_t)N * 4);
  int*    rowptr= (int*)   carve((size_t)(N + 1) * 4);
  int*    pos   = (int*)   carve((size_t)N * 4);
  int*    csr   = (int*)   carve((size_t)ET * 4);
  int*    bsum  = (int*)   carve(64 * 4);

  // ---- prep (x->fp16, pack W1/W2, zero deg) : 1 dispatch ----
  prep_kernel<<<2048, 256, 0, stream>>>(x, xh, (size_t)N * IN / 4,
                                        W1, W1f, IN * HC, HC,
                                        W2, W2f, HC * C, C,
                                        deg, N);

  // ---- CSR build : 4 dispatches ----
  build_deg<<<(ET + 255) / 256, 256, 0, stream>>>(ei, E, N, deg);
  scan_phase1<<<NB, 1024, 0, stream>>>(deg, rowptr, bsum, N);
  scan_phase3<<<NB, 1024, 0, stream>>>(rowptr, pos, bsum, NB, N);
  build_csr<<<(ET + 255) / 256, 256, 0, stream>>>(ei, E, N, pos, csr);

  // ---- layer 1 ----
  dim3 g1((N + 63) / 64, HC / 64);
  gemm_mfma<<<g1, 256, 0, stream>>>(xh, W1f, hx1h, att_src1, att_dst1,
                                    as1, ad1, N, HC, IN, 4);
  fused_agg1<<<(N + 3) / 4, 256, 0, stream>>>(rowptr, csr, as1, ad1, hx1h, b1, h1h, N);

  // ---- layer 2 ----
  dim3 g2((N + 63) / 64, C / 64);
  gemm_mfma<<<g2, 256, 0, stream>>>(h1h, W2f, hx2h, att_src2, att_dst2,
                                    as2, ad2, N, C, HC, 1);
  fused_agg2<<<(N + 3) / 4, 256, 0, stream>>>(rowptr, csr, as2, ad2, hx2h, b2, out, N);
}